// Round 1
// 174.534 us; speedup vs baseline: 1.0569x; 1.0569x over previous
//
#include <hip/hip_runtime.h>

#define NND 8192
#define KNBR 8
#define DD 128
#define EPSF 1e-5f
#define BSTRF 136   // K=128 LDS row stride in shorts (68 dwords = 4 mod 32 banks -> free 2-way)

typedef __attribute__((ext_vector_type(8))) short bf16x8;
typedef __attribute__((ext_vector_type(4))) float f32x4;

__device__ __forceinline__ unsigned short f2bf(float f) {
    unsigned u = __float_as_uint(f);
    u += 0x7FFF + ((u >> 16) & 1);   // round-to-nearest-even
    return (unsigned short)(u >> 16);
}

__device__ __forceinline__ bf16x8 cvt8(const float* __restrict__ p) {
    float4 lo = *(const float4*)p;
    float4 hi = *(const float4*)(p + 4);
    bf16x8 r;
    r[0] = f2bf(lo.x); r[1] = f2bf(lo.y); r[2] = f2bf(lo.z); r[3] = f2bf(lo.w);
    r[4] = f2bf(hi.x); r[5] = f2bf(hi.y); r[6] = f2bf(hi.z); r[7] = f2bf(hi.w);
    return r;
}

// Stage a 128(out-col) x 128(K) fp32 weight slice into LDS as bf16.
// 256 threads: thread t -> row t>>1, 64-elem half (t&1).
__device__ __forceinline__ void stage_cvt(unsigned short* sh, const float* __restrict__ W,
                                          int wstr, int tid) {
    int r = tid >> 1, c = (tid & 1) * 64;
    const float* src = W + (size_t)r * wstr + c;
    unsigned short* d = sh + r * BSTRF + c;
#pragma unroll
    for (int i = 0; i < 8; ++i)
        *(bf16x8*)(d + i * 8) = cvt8(src + i * 8);
}

// Full-width wave GEMM: 16 rows x 128 cols per wave, K=128, A fp32 global
// converted once. Layouts as baseline (m89/m91): A row=lane&15, k=q*8+j;
// B from LDS row = out-col; C/D col=lane&15, row=q*4+reg.
__device__ __forceinline__ void mma_fw(const float* __restrict__ A, int rowBase,
        const unsigned short* shB, int lane, f32x4* acc) {
    int idx = lane & 15, q = lane >> 4;
    const float* Arow = A + (size_t)(rowBase + idx) * DD;
#pragma unroll
    for (int s = 0; s < 4; ++s) {
        bf16x8 af = cvt8(Arow + s * 32 + q * 8);
#pragma unroll
        for (int ct = 0; ct < 8; ++ct) {
            bf16x8 bf = *(const bf16x8*)(shB + (ct * 16 + idx) * BSTRF + s * 32 + q * 8);
            acc[ct] = __builtin_amdgcn_mfma_f32_16x16x32_bf16(af, bf, acc[ct], 0, 0, 0);
        }
    }
}

__device__ __forceinline__ void store_fw(float* __restrict__ out, int ostride, int oOff,
        int rowBase, int lane, const f32x4* acc, const float* __restrict__ bias, bool relu) {
    int idx = lane & 15, q = lane >> 4;
#pragma unroll
    for (int ct = 0; ct < 8; ++ct) {
        float b = bias[ct * 16 + idx];
#pragma unroll
        for (int r = 0; r < 4; ++r) {
            float v = acc[ct][r] + b;
            if (relu) v = fmaxf(v, 0.f);
            out[(size_t)(rowBase + q * 4 + r) * ostride + oOff + ct * 16 + idx] = v;
        }
    }
}

// Fused epilogue: v = relu(acc + bias) + resid[row];  out = LN(v)*g + b.
// Each output row (rowBase + q*4 + r) is held by the 16 lanes of one idx-group
// (8 cols each) -> row reduction = 8-term register sum + 4-step shfl_xor.
__device__ __forceinline__ void lnstore_fw(float* __restrict__ out, int ostride, int oOff,
        const float* __restrict__ resid, int rowBase, int lane, f32x4* acc,
        const float* __restrict__ bias, const float* __restrict__ g,
        const float* __restrict__ bv) {
    int idx = lane & 15, q = lane >> 4;
    float rsum[4] = {0.f, 0.f, 0.f, 0.f};
#pragma unroll
    for (int ct = 0; ct < 8; ++ct) {
        float b = bias[ct * 16 + idx];
#pragma unroll
        for (int r = 0; r < 4; ++r) {
            float t = fmaxf(acc[ct][r] + b, 0.f)
                    + resid[(size_t)(rowBase + q * 4 + r) * DD + ct * 16 + idx];
            acc[ct][r] = t;
            rsum[r] += t;
        }
    }
#pragma unroll
    for (int r = 0; r < 4; ++r)
#pragma unroll
        for (int m = 1; m < 16; m <<= 1) rsum[r] += __shfl_xor(rsum[r], m, 64);
    float mu[4];
#pragma unroll
    for (int r = 0; r < 4; ++r) mu[r] = rsum[r] * (1.f / 128.f);
    float var[4] = {0.f, 0.f, 0.f, 0.f};
#pragma unroll
    for (int ct = 0; ct < 8; ++ct)
#pragma unroll
        for (int r = 0; r < 4; ++r) {
            float d = acc[ct][r] - mu[r];
            var[r] += d * d;
        }
#pragma unroll
    for (int r = 0; r < 4; ++r)
#pragma unroll
        for (int m = 1; m < 16; m <<= 1) var[r] += __shfl_xor(var[r], m, 64);
    float rs[4];
#pragma unroll
    for (int r = 0; r < 4; ++r) rs[r] = rsqrtf(var[r] * (1.f / 128.f) + EPSF);
#pragma unroll
    for (int ct = 0; ct < 8; ++ct) {
        float gg = g[ct * 16 + idx], bb = bv[ct * 16 + idx];
#pragma unroll
        for (int r = 0; r < 4; ++r)
            out[(size_t)(rowBase + q * 4 + r) * ostride + oOff + ct * 16 + idx]
                = (acc[ct][r] - mu[r]) * rs[r] * gg + bb;
    }
}

// ---------------------------------------------------------------------------
// mega: grid (128, 3).  y0: G0 = x@gcnW0^T + gB0
//                       y1: E1 = relu(x@poolW^T + pB)
//                       y2: S1p = x@mW0L^T + mB0
// Degree/dedupe folded into y0 blocks x<32 (consumed first by kernel 3).
// ---------------------------------------------------------------------------
__global__ __launch_bounds__(256)
void mega_gemm(const float* __restrict__ x,
               const float* __restrict__ gcnW, const float* __restrict__ poolW,
               const float* __restrict__ mW,
               const float* __restrict__ gB0, const float* __restrict__ pB,
               const float* __restrict__ mB0,
               const int* __restrict__ neigh, const int* __restrict__ cnt,
               float* __restrict__ dinv, int* __restrict__ kept,
               float* __restrict__ G, float* __restrict__ E, float* __restrict__ S) {
    __shared__ unsigned short shB[128 * BSTRF];
    const int tid = threadIdx.x;
    const int grp = blockIdx.y;
    const float* W; const float* bias; float* dst; int wstr; bool relu = false;
    if (grp == 0)      { W = gcnW;  bias = gB0; dst = G; wstr = 128; }
    else if (grp == 1) { W = poolW; bias = pB;  dst = E; wstr = 128; relu = true; }
    else               { W = mW;    bias = mB0; dst = S; wstr = 256; }
    stage_cvt(shB, W, wstr, tid);
    __syncthreads();
    const int lane = tid & 63, w = tid >> 6;
    const int rowBase = ((int)blockIdx.x * 4 + w) * 16;
    f32x4 acc[8];
#pragma unroll
    for (int i = 0; i < 8; ++i) acc[i] = (f32x4){0.f, 0.f, 0.f, 0.f};
    mma_fw(x, rowBase, shB, lane, acc);
    store_fw(dst, DD, 0, rowBase, lane, acc, bias, relu);

    if (grp == 0 && blockIdx.x < 32) {
        int i = (int)blockIdx.x * 256 + tid;
        int c = cnt[i];
        int nb[KNBR];
#pragma unroll
        for (int j = 0; j < KNBR; ++j) nb[j] = neigh[i * KNBR + j];
        int mask = 0, deg = 1;
#pragma unroll
        for (int j = 0; j < KNBR; ++j) {
            if (j < c) {
                int v = nb[j];
                bool dup = (v == i);
                for (int jj = 0; jj < j; ++jj)
                    if (nb[jj] == v) { dup = true; }
                if (!dup) { mask |= (1 << j); deg++; }
            }
        }
        dinv[i] = rsqrtf((float)deg);
        kept[i] = mask;
    }
}

// step4: grid (128, 2).  y0: S1 = relu(S1p + P1@mW0R^T)   (RMW)
//                        y1: G1 = H1@gcnW1^T + gB1
__global__ __launch_bounds__(256)
void gemm_step4(const float* __restrict__ P, const float* __restrict__ H1,
                const float* __restrict__ mW, const float* __restrict__ gcnW,
                const float* __restrict__ gB1,
                float* __restrict__ S, float* __restrict__ G) {
    __shared__ unsigned short shB[128 * BSTRF];
    const int tid = threadIdx.x;
    const int lane = tid & 63, w = tid >> 6;
    const int rowBase = ((int)blockIdx.x * 4 + w) * 16;
    f32x4 acc[8];
#pragma unroll
    for (int i = 0; i < 8; ++i) acc[i] = (f32x4){0.f, 0.f, 0.f, 0.f};
    if (blockIdx.y == 0) {
        stage_cvt(shB, mW + 128, 256, tid);     // mW0 right half
        __syncthreads();
        mma_fw(P, rowBase, shB, lane, acc);
        int idx = lane & 15, q = lane >> 4;
#pragma unroll
        for (int ct = 0; ct < 8; ++ct)
#pragma unroll
            for (int r = 0; r < 4; ++r) {
                size_t o = (size_t)(rowBase + q * 4 + r) * DD + ct * 16 + idx;
                S[o] = fmaxf(S[o] + acc[ct][r], 0.f);
            }
    } else {
        stage_cvt(shB, gcnW + 16384, 128, tid); // gcnW1
        __syncthreads();
        mma_fw(H1, rowBase, shB, lane, acc);
        store_fw(G, DD, 0, rowBase, lane, acc, gB1, false);
    }
}

// step6: grid (128, 2).
//  y0: S2 = LN(relu([S1|P2]@mW1^T + mB1) + S1)   (K=256 concat, LN fused)
//  y1: G2 = H2@gcnW2^T + gB2
__global__ __launch_bounds__(256)
void gemm_step6(const float* __restrict__ S1, const float* __restrict__ P,
                const float* __restrict__ H2,
                const float* __restrict__ mW, const float* __restrict__ gcnW,
                const float* __restrict__ mB1, const float* __restrict__ gB2,
                const float* __restrict__ sg, const float* __restrict__ sb,
                float* __restrict__ S2, float* __restrict__ G) {
    __shared__ unsigned short shB[128 * BSTRF];
    const int tid = threadIdx.x;
    const int lane = tid & 63, w = tid >> 6;
    const int rowBase = ((int)blockIdx.x * 4 + w) * 16;
    f32x4 acc[8];
#pragma unroll
    for (int i = 0; i < 8; ++i) acc[i] = (f32x4){0.f, 0.f, 0.f, 0.f};
    if (blockIdx.y == 0) {
        stage_cvt(shB, mW + 32768, 256, tid);         // mW1 left (S1 part)
        __syncthreads();
        mma_fw(S1, rowBase, shB, lane, acc);
        __syncthreads();
        stage_cvt(shB, mW + 32768 + 128, 256, tid);   // mW1 right (pool part)
        __syncthreads();
        mma_fw(P, rowBase, shB, lane, acc);
        lnstore_fw(S2, DD, 0, S1, rowBase, lane, acc, mB1, sg, sb);
    } else {
        stage_cvt(shB, gcnW + 32768, 128, tid);       // gcnW2
        __syncthreads();
        mma_fw(H2, rowBase, shB, lane, acc);
        store_fw(G, DD, 0, rowBase, lane, acc, gB2, false);
    }
}

// final: grid (128). out[:, D:] = LN(relu([S2|P3]@mW2^T + mB2) + S2)
__global__ __launch_bounds__(256)
void gemm_final(const float* __restrict__ S2, const float* __restrict__ P,
                const float* __restrict__ mW, const float* __restrict__ mB2,
                const float* __restrict__ sg2, const float* __restrict__ sb2,
                float* __restrict__ out) {
    __shared__ unsigned short shB[128 * BSTRF];
    const int tid = threadIdx.x;
    const int lane = tid & 63, w = tid >> 6;
    const int rowBase = ((int)blockIdx.x * 4 + w) * 16;
    f32x4 acc[8];
#pragma unroll
    for (int i = 0; i < 8; ++i) acc[i] = (f32x4){0.f, 0.f, 0.f, 0.f};
    stage_cvt(shB, mW + 65536, 256, tid);         // mW2 left
    __syncthreads();
    mma_fw(S2, rowBase, shB, lane, acc);
    __syncthreads();
    stage_cvt(shB, mW + 65536 + 128, 256, tid);   // mW2 right
    __syncthreads();
    mma_fw(P, rowBase, shB, lane, acc);
    lnstore_fw(out, 2 * DD, DD, S2, rowBase, lane, acc, mB2, sg2, sb2);
}

// ---------------------------------------------------------------------------
// Row-wise (fp32, one wave per row, float2 per lane) — unchanged.
// ---------------------------------------------------------------------------
__device__ __forceinline__ float wave_sum(float s) {
#pragma unroll
    for (int m = 1; m < 64; m <<= 1) s += __shfl_xor(s, m, 64);
    return s;
}

__device__ __forceinline__ void prop_ln_row(int row, int lane,
        const float* __restrict__ nxt, const float* __restrict__ resid,
        const float* __restrict__ dinv, const int* __restrict__ kept,
        const int* __restrict__ neigh,
        const float* __restrict__ g, const float* __restrict__ b,
        float* __restrict__ out, int oStride, int oOff) {
    const float2* nxt2 = (const float2*)nxt;
    float di = dinv[row];
    int km = kept[row];
    float2 self = nxt2[row * 64 + lane];
    float ax = di * self.x, ay = di * self.y;
#pragma unroll
    for (int j = 0; j < KNBR; ++j) {
        if (km & (1 << j)) {
            int nb = neigh[row * KNBR + j];
            float dn = dinv[nb];
            float2 v = nxt2[nb * 64 + lane];
            ax = fmaf(dn, v.x, ax);
            ay = fmaf(dn, v.y, ay);
        }
    }
    float2 r = ((const float2*)resid)[row * 64 + lane];
    float vx = fmaxf(di * ax, 0.f) + r.x;
    float vy = fmaxf(di * ay, 0.f) + r.y;
    float mu = wave_sum(vx + vy) * (1.f / 128.f);
    float dx = vx - mu, dy = vy - mu;
    float var = wave_sum(dx * dx + dy * dy) * (1.f / 128.f);
    float rs = rsqrtf(var + EPSF);
    float2 gg = ((const float2*)g)[lane];
    float2 bb = ((const float2*)b)[lane];
    float2 o;
    o.x = dx * rs * gg.x + bb.x;
    o.y = dy * rs * gg.y + bb.y;
    *reinterpret_cast<float2*>(out + (size_t)row * oStride + oOff + lane * 2) = o;
}

__device__ __forceinline__ void pool_row(int row, int lane,
        const float* __restrict__ enc, const int* __restrict__ neigh,
        const int* __restrict__ cnt, float* __restrict__ P) {
    int c = cnt[row];
    float2 acc = make_float2(0.f, 0.f);
    if (c > 0) {
        acc = make_float2(-1e30f, -1e30f);
        for (int j = 0; j < c; ++j) {
            int nb = neigh[row * KNBR + j];
            float2 v = ((const float2*)enc)[nb * 64 + lane];
            acc.x = fmaxf(acc.x, v.x);
            acc.y = fmaxf(acc.y, v.y);
        }
    }
    ((float2*)P)[row * 64 + lane] = acc;
}

__global__ __launch_bounds__(256)
void prop_pool_kernel(const float* __restrict__ nxt, const float* __restrict__ resid,
                      const float* __restrict__ dinv, const int* __restrict__ kept,
                      const int* __restrict__ neigh, const int* __restrict__ cnt,
                      const float* __restrict__ g, const float* __restrict__ b,
                      float* __restrict__ outH, int oStride, int oOff,
                      const float* __restrict__ enc, float* __restrict__ P) {
    int row = blockIdx.x * 4 + (threadIdx.x >> 6);
    int lane = threadIdx.x & 63;
    prop_ln_row(row, lane, nxt, resid, dinv, kept, neigh, g, b, outH, oStride, oOff);
    pool_row(row, lane, enc, neigh, cnt, P);
}

extern "C" void kernel_launch(void* const* d_in, const int* in_sizes, int n_in,
                              void* d_out, int out_size, void* d_ws, size_t ws_size,
                              hipStream_t stream) {
    (void)in_sizes; (void)n_in; (void)out_size; (void)ws_size;
    const float* x      = (const float*)d_in[0];
    const int*   neigh  = (const int*)d_in[1];
    const int*   cnt    = (const int*)d_in[2];
    const float* gcnW   = (const float*)d_in[3];
    const float* gcnB   = (const float*)d_in[4];
    const float* gcnG   = (const float*)d_in[5];
    const float* gcnBb  = (const float*)d_in[6];
    const float* poolW  = (const float*)d_in[7];
    const float* poolB  = (const float*)d_in[8];
    const float* mW     = (const float*)d_in[9];
    const float* mB     = (const float*)d_in[10];
    const float* sg     = (const float*)d_in[11];
    const float* sb     = (const float*)d_in[12];
    float* out = (float*)d_out;

    char* ws = (char*)d_ws;
    float* dinv = (float*)ws;                          // 32 KB
    int*   kept = (int*)(ws + 32 * 1024);              // 32 KB
    float* G  = (float*)(ws + 448 * 1024);             // 4 MB each
    float* H1 = G  + NND * DD;
    float* H2 = H1 + NND * DD;
    float* E  = H2 + NND * DD;
    float* P  = E  + NND * DD;
    float* S1 = P  + NND * DD;
    float* S2 = S1 + NND * DD;

    dim3 blk(256);
    dim3 rgrid(NND / 4);

    // 1. [G0 | E1 | S1p] from x  (+ degree/dedupe folded in)
    mega_gemm<<<dim3(128, 3), blk, 0, stream>>>(x, gcnW, poolW, mW, gcnB, poolB, mB,
                                                neigh, cnt, dinv, kept, G, E, S1);
    // 2. H1 = propLN(G0, resid=G0); P1 = pool(E1)
    prop_pool_kernel<<<rgrid, blk, 0, stream>>>(G, G, dinv, kept, neigh, cnt,
                                                gcnG, gcnBb, H1, DD, 0, E, P);
    // 3. S1 = relu(S1p + P1@mW0R^T); G1 = H1@gcnW1^T + b1
    gemm_step4<<<dim3(128, 2), blk, 0, stream>>>(P, H1, mW, gcnW, gcnB + DD, S1, G);
    // 4. H2 = propLN(G1, resid=H1); P2 = pool(S1)
    prop_pool_kernel<<<rgrid, blk, 0, stream>>>(G, H1, dinv, kept, neigh, cnt,
                                                gcnG + DD, gcnBb + DD, H2, DD, 0,
                                                S1, P);
    // 5. S2 = LN(relu([S1|P2]@mW1^T + mB1) + S1); G2 = H2@gcnW2^T + b2
    gemm_step6<<<dim3(128, 2), blk, 0, stream>>>(S1, P, H2, mW, gcnW, mB + DD,
                                                 gcnB + 2 * DD, sg, sb, S2, G);
    // 6. outL = propLN(G2, resid=H2); P3 = pool(S2)
    prop_pool_kernel<<<rgrid, blk, 0, stream>>>(G, H2, dinv, kept, neigh, cnt,
                                                gcnG + 2 * DD, gcnBb + 2 * DD,
                                                out, 2 * DD, 0, S2, P);
    // 7. outR = LN(relu([S2|P3]@mW2^T + mB2) + S2)
    gemm_final<<<dim3(128), blk, 0, stream>>>(S2, P, mW, mB + 2 * DD,
                                              sg + DD, sb + DD, out);
}

// Round 2
// 152.001 us; speedup vs baseline: 1.2136x; 1.1482x over previous
//
#include <hip/hip_runtime.h>

#define NND 8192
#define KNBR 8
#define DD 128
#define EPSF 1e-5f
#define BSTRF 136   // K=128 LDS row stride in shorts (68 dwords = 4 mod 32 banks -> free 2-way)
#define TILE (128 * BSTRF)

typedef __attribute__((ext_vector_type(8))) short bf16x8;
typedef __attribute__((ext_vector_type(4))) float f32x4;

__device__ __forceinline__ unsigned short f2bf(float f) {
    unsigned u = __float_as_uint(f);
    u += 0x7FFF + ((u >> 16) & 1);   // round-to-nearest-even
    return (unsigned short)(u >> 16);
}

__device__ __forceinline__ bf16x8 cvt8(const float* __restrict__ p) {
    float4 lo = *(const float4*)p;
    float4 hi = *(const float4*)(p + 4);
    bf16x8 r;
    r[0] = f2bf(lo.x); r[1] = f2bf(lo.y); r[2] = f2bf(lo.z); r[3] = f2bf(lo.w);
    r[4] = f2bf(hi.x); r[5] = f2bf(hi.y); r[6] = f2bf(hi.z); r[7] = f2bf(hi.w);
    return r;
}

// Stage a 128(out-col) x 128(K) fp32 weight slice into LDS as bf16.
__device__ __forceinline__ void stage_cvt(unsigned short* sh, const float* __restrict__ W,
                                          int wstr, int tid) {
    int r = tid >> 1, c = (tid & 1) * 64;
    const float* src = W + (size_t)r * wstr + c;
    unsigned short* d = sh + r * BSTRF + c;
#pragma unroll
    for (int i = 0; i < 8; ++i)
        *(bf16x8*)(d + i * 8) = cvt8(src + i * 8);
}

// Full-width wave GEMM, A fp32 (converted) — used only for x.
__device__ __forceinline__ void mma_f32(const float* __restrict__ A, int rowBase,
        const unsigned short* shB, int lane, f32x4* acc) {
    int idx = lane & 15, q = lane >> 4;
    const float* Arow = A + (size_t)(rowBase + idx) * DD;
#pragma unroll
    for (int s = 0; s < 4; ++s) {
        bf16x8 af = cvt8(Arow + s * 32 + q * 8);
#pragma unroll
        for (int ct = 0; ct < 8; ++ct) {
            bf16x8 bf = *(const bf16x8*)(shB + (ct * 16 + idx) * BSTRF + s * 32 + q * 8);
            acc[ct] = __builtin_amdgcn_mfma_f32_16x16x32_bf16(af, bf, acc[ct], 0, 0, 0);
        }
    }
}

// Full-width wave GEMM, A bf16 direct (no cvt), A-frags hoisted.
__device__ __forceinline__ void mma_bf(const unsigned short* __restrict__ A, int rowBase,
        const unsigned short* shB, int lane, f32x4* acc) {
    int idx = lane & 15, q = lane >> 4;
    const unsigned short* Arow = A + (size_t)(rowBase + idx) * DD;
    bf16x8 af[4];
#pragma unroll
    for (int s = 0; s < 4; ++s) af[s] = *(const bf16x8*)(Arow + s * 32 + q * 8);
#pragma unroll
    for (int s = 0; s < 4; ++s)
#pragma unroll
        for (int ct = 0; ct < 8; ++ct) {
            bf16x8 bf = *(const bf16x8*)(shB + (ct * 16 + idx) * BSTRF + s * 32 + q * 8);
            acc[ct] = __builtin_amdgcn_mfma_f32_16x16x32_bf16(af[s], bf, acc[ct], 0, 0, 0);
        }
}

__device__ __forceinline__ void store_fw(float* __restrict__ out, int ostride, int oOff,
        int rowBase, int lane, const f32x4* acc, const float* __restrict__ bias, bool relu) {
    int idx = lane & 15, q = lane >> 4;
#pragma unroll
    for (int ct = 0; ct < 8; ++ct) {
        float b = bias[ct * 16 + idx];
#pragma unroll
        for (int r = 0; r < 4; ++r) {
            float v = acc[ct][r] + b;
            if (relu) v = fmaxf(v, 0.f);
            out[(size_t)(rowBase + q * 4 + r) * ostride + oOff + ct * 16 + idx] = v;
        }
    }
}

// bf16-only store (relu), for tensors consumed solely by gathers/GEMM-A.
__device__ __forceinline__ void store_fw_b16(unsigned short* __restrict__ out,
        int rowBase, int lane, const f32x4* acc, const float* __restrict__ bias) {
    int idx = lane & 15, q = lane >> 4;
#pragma unroll
    for (int ct = 0; ct < 8; ++ct) {
        float b = bias[ct * 16 + idx];
#pragma unroll
        for (int r = 0; r < 4; ++r)
            out[(size_t)(rowBase + q * 4 + r) * DD + ct * 16 + idx]
                = f2bf(fmaxf(acc[ct][r] + b, 0.f));
    }
}

// Fused epilogue: v = relu(acc+bias) + resid;  out = LN(v)*g + b  (+ optional bf16 copy).
__device__ __forceinline__ void lnstore_fw(float* __restrict__ out, int ostride, int oOff,
        const float* __restrict__ resid, int rowBase, int lane, f32x4* acc,
        const float* __restrict__ bias, const float* __restrict__ g,
        const float* __restrict__ bv, unsigned short* __restrict__ outB) {
    int idx = lane & 15, q = lane >> 4;
    float rsum[4] = {0.f, 0.f, 0.f, 0.f};
#pragma unroll
    for (int ct = 0; ct < 8; ++ct) {
        float b = bias[ct * 16 + idx];
#pragma unroll
        for (int r = 0; r < 4; ++r) {
            float t = fmaxf(acc[ct][r] + b, 0.f)
                    + resid[(size_t)(rowBase + q * 4 + r) * DD + ct * 16 + idx];
            acc[ct][r] = t;
            rsum[r] += t;
        }
    }
#pragma unroll
    for (int r = 0; r < 4; ++r)
#pragma unroll
        for (int m = 1; m < 16; m <<= 1) rsum[r] += __shfl_xor(rsum[r], m, 64);
    float mu[4];
#pragma unroll
    for (int r = 0; r < 4; ++r) mu[r] = rsum[r] * (1.f / 128.f);
    float var[4] = {0.f, 0.f, 0.f, 0.f};
#pragma unroll
    for (int ct = 0; ct < 8; ++ct)
#pragma unroll
        for (int r = 0; r < 4; ++r) {
            float d = acc[ct][r] - mu[r];
            var[r] += d * d;
        }
#pragma unroll
    for (int r = 0; r < 4; ++r)
#pragma unroll
        for (int m = 1; m < 16; m <<= 1) var[r] += __shfl_xor(var[r], m, 64);
    float rs[4];
#pragma unroll
    for (int r = 0; r < 4; ++r) rs[r] = rsqrtf(var[r] * (1.f / 128.f) + EPSF);
#pragma unroll
    for (int ct = 0; ct < 8; ++ct) {
        float gg = g[ct * 16 + idx], bb = bv[ct * 16 + idx];
#pragma unroll
        for (int r = 0; r < 4; ++r) {
            float o = (acc[ct][r] - mu[r]) * rs[r] * gg + bb;
            size_t row = (size_t)(rowBase + q * 4 + r);
            out[row * ostride + oOff + ct * 16 + idx] = o;
            if (outB) outB[row * DD + ct * 16 + idx] = f2bf(o);
        }
    }
}

// ---------------------------------------------------------------------------
// mega: grid (128, 3). y0: G0 = x@gcnW0^T + gB0 (+degree/dedupe for x<32)
//                      y1: E1b = bf16(relu(x@poolW^T + pB))
//                      y2: S1p = x@mW0L^T + mB0
// ---------------------------------------------------------------------------
__global__ __launch_bounds__(256)
void mega_gemm(const float* __restrict__ x,
               const float* __restrict__ gcnW, const float* __restrict__ poolW,
               const float* __restrict__ mW,
               const float* __restrict__ gB0, const float* __restrict__ pB,
               const float* __restrict__ mB0,
               const int* __restrict__ neigh, const int* __restrict__ cnt,
               float* __restrict__ dinv, int* __restrict__ kept,
               float* __restrict__ G, unsigned short* __restrict__ E1b,
               float* __restrict__ S) {
    __shared__ unsigned short shB[TILE];
    const int tid = threadIdx.x;
    const int grp = blockIdx.y;
    const float* W; int wstr;
    if (grp == 0)      { W = gcnW;  wstr = 128; }
    else if (grp == 1) { W = poolW; wstr = 128; }
    else               { W = mW;    wstr = 256; }
    stage_cvt(shB, W, wstr, tid);
    __syncthreads();
    const int lane = tid & 63, w = tid >> 6;
    const int rowBase = ((int)blockIdx.x * 4 + w) * 16;
    f32x4 acc[8];
#pragma unroll
    for (int i = 0; i < 8; ++i) acc[i] = (f32x4){0.f, 0.f, 0.f, 0.f};
    mma_f32(x, rowBase, shB, lane, acc);
    if (grp == 0)      store_fw(G, DD, 0, rowBase, lane, acc, gB0, false);
    else if (grp == 1) store_fw_b16(E1b, rowBase, lane, acc, pB);
    else               store_fw(S, DD, 0, rowBase, lane, acc, mB0, false);

    if (grp == 0 && blockIdx.x < 32) {
        int i = (int)blockIdx.x * 256 + tid;
        int c = cnt[i];
        int nb[KNBR];
#pragma unroll
        for (int j = 0; j < KNBR; ++j) nb[j] = neigh[i * KNBR + j];
        int mask = 0, deg = 1;
#pragma unroll
        for (int j = 0; j < KNBR; ++j) {
            if (j < c) {
                int v = nb[j];
                bool dup = (v == i);
                for (int jj = 0; jj < j; ++jj)
                    if (nb[jj] == v) { dup = true; }
                if (!dup) { mask |= (1 << j); deg++; }
            }
        }
        dinv[i] = rsqrtf((float)deg);
        kept[i] = mask;
    }
}

// step4: grid (128, 2). y0: S1 = relu(S1p + P1b@mW0R^T) (RMW) + bf16 copy
//                       y1: G1 = H1b@gcnW1^T + gB1
__global__ __launch_bounds__(256)
void gemm_step4(const unsigned short* __restrict__ Pb, const unsigned short* __restrict__ H1b,
                const float* __restrict__ mW, const float* __restrict__ gcnW,
                const float* __restrict__ gB1,
                float* __restrict__ S, unsigned short* __restrict__ S1b,
                float* __restrict__ G) {
    __shared__ unsigned short shB[TILE];
    const int tid = threadIdx.x;
    const int lane = tid & 63, w = tid >> 6;
    const int rowBase = ((int)blockIdx.x * 4 + w) * 16;
    f32x4 acc[8];
#pragma unroll
    for (int i = 0; i < 8; ++i) acc[i] = (f32x4){0.f, 0.f, 0.f, 0.f};
    if (blockIdx.y == 0) {
        stage_cvt(shB, mW + 128, 256, tid);     // mW0 right half
        __syncthreads();
        mma_bf(Pb, rowBase, shB, lane, acc);
        int idx = lane & 15, q = lane >> 4;
#pragma unroll
        for (int ct = 0; ct < 8; ++ct)
#pragma unroll
            for (int r = 0; r < 4; ++r) {
                size_t o = (size_t)(rowBase + q * 4 + r) * DD + ct * 16 + idx;
                float v = fmaxf(S[o] + acc[ct][r], 0.f);
                S[o] = v;
                S1b[o] = f2bf(v);
            }
    } else {
        stage_cvt(shB, gcnW + 16384, 128, tid); // gcnW1
        __syncthreads();
        mma_bf(H1b, rowBase, shB, lane, acc);
        store_fw(G, DD, 0, rowBase, lane, acc, gB1, false);
    }
}

// step6: grid (128, 2).
//  y0: S2 = LN(relu([S1|P2]@mW1^T + mB1) + S1) (+bf16 copy); both B halves staged at once
//  y1: G2 = H2b@gcnW2^T + gB2
__global__ __launch_bounds__(256)
void gemm_step6(const unsigned short* __restrict__ S1b, const unsigned short* __restrict__ Pb,
                const unsigned short* __restrict__ H2b, const float* __restrict__ S1,
                const float* __restrict__ mW, const float* __restrict__ gcnW,
                const float* __restrict__ mB1, const float* __restrict__ gB2,
                const float* __restrict__ sg, const float* __restrict__ sb,
                float* __restrict__ S2, unsigned short* __restrict__ S2b,
                float* __restrict__ G) {
    __shared__ unsigned short shB[2 * TILE];
    const int tid = threadIdx.x;
    const int lane = tid & 63, w = tid >> 6;
    const int rowBase = ((int)blockIdx.x * 4 + w) * 16;
    f32x4 acc[8];
#pragma unroll
    for (int i = 0; i < 8; ++i) acc[i] = (f32x4){0.f, 0.f, 0.f, 0.f};
    if (blockIdx.y == 0) {
        stage_cvt(shB, mW + 32768, 256, tid);              // mW1 left (S1)
        stage_cvt(shB + TILE, mW + 32768 + 128, 256, tid); // mW1 right (pool)
        __syncthreads();
        mma_bf(S1b, rowBase, shB, lane, acc);
        mma_bf(Pb, rowBase, shB + TILE, lane, acc);
        lnstore_fw(S2, DD, 0, S1, rowBase, lane, acc, mB1, sg, sb, S2b);
    } else {
        stage_cvt(shB, gcnW + 32768, 128, tid);            // gcnW2
        __syncthreads();
        mma_bf(H2b, rowBase, shB, lane, acc);
        store_fw(G, DD, 0, rowBase, lane, acc, gB2, false);
    }
}

// final: grid (128). out[:, D:] = LN(relu([S2|P3]@mW2^T + mB2) + S2)
__global__ __launch_bounds__(256)
void gemm_final(const unsigned short* __restrict__ S2b, const unsigned short* __restrict__ Pb,
                const float* __restrict__ S2,
                const float* __restrict__ mW, const float* __restrict__ mB2,
                const float* __restrict__ sg2, const float* __restrict__ sb2,
                float* __restrict__ out) {
    __shared__ unsigned short shB[2 * TILE];
    const int tid = threadIdx.x;
    const int lane = tid & 63, w = tid >> 6;
    const int rowBase = ((int)blockIdx.x * 4 + w) * 16;
    f32x4 acc[8];
#pragma unroll
    for (int i = 0; i < 8; ++i) acc[i] = (f32x4){0.f, 0.f, 0.f, 0.f};
    stage_cvt(shB, mW + 65536, 256, tid);              // mW2 left
    stage_cvt(shB + TILE, mW + 65536 + 128, 256, tid); // mW2 right
    __syncthreads();
    mma_bf(S2b, rowBase, shB, lane, acc);
    mma_bf(Pb, rowBase, shB + TILE, lane, acc);
    lnstore_fw(out, 2 * DD, DD, S2, rowBase, lane, acc, mB2, sg2, sb2, nullptr);
}

// ---------------------------------------------------------------------------
// Row-wise: prop+LN (fp32 gathers, de-serialized) and bf16 max-pool.
// ---------------------------------------------------------------------------
__device__ __forceinline__ float wave_sum(float s) {
#pragma unroll
    for (int m = 1; m < 64; m <<= 1) s += __shfl_xor(s, m, 64);
    return s;
}

__device__ __forceinline__ void prop_ln_row(int row, int lane,
        const float* __restrict__ nxt, const float* __restrict__ resid,
        const float* __restrict__ dinv, const int* __restrict__ kept,
        const int* __restrict__ neigh,
        const float* __restrict__ g, const float* __restrict__ b,
        float* __restrict__ out, int oStride, int oOff,
        unsigned short* __restrict__ outB) {
    const float2* nxt2 = (const float2*)nxt;
    float di = dinv[row];
    int km = kept[row];
    int idxs[KNBR]; float wj[KNBR];
#pragma unroll
    for (int j = 0; j < KNBR; ++j) {
        int nb = neigh[row * KNBR + j];
        bool k = (km >> j) & 1;
        idxs[j] = k ? nb : row;          // dead slots re-read self row (L1 hit)
        wj[j] = k ? dinv[nb] : 0.f;
    }
    float2 vv[KNBR];
#pragma unroll
    for (int j = 0; j < KNBR; ++j) vv[j] = nxt2[(size_t)idxs[j] * 64 + lane];
    float2 self = nxt2[(size_t)row * 64 + lane];
    float ax = di * self.x, ay = di * self.y;
#pragma unroll
    for (int j = 0; j < KNBR; ++j) {
        ax = fmaf(wj[j], vv[j].x, ax);
        ay = fmaf(wj[j], vv[j].y, ay);
    }
    float2 r = ((const float2*)resid)[(size_t)row * 64 + lane];
    float vx = fmaxf(di * ax, 0.f) + r.x;
    float vy = fmaxf(di * ay, 0.f) + r.y;
    float mu = wave_sum(vx + vy) * (1.f / 128.f);
    float dx = vx - mu, dy = vy - mu;
    float var = wave_sum(dx * dx + dy * dy) * (1.f / 128.f);
    float rs = rsqrtf(var + EPSF);
    float2 gg = ((const float2*)g)[lane];
    float2 bb = ((const float2*)b)[lane];
    float2 o;
    o.x = dx * rs * gg.x + bb.x;
    o.y = dy * rs * gg.y + bb.y;
    *reinterpret_cast<float2*>(out + (size_t)row * oStride + oOff + lane * 2) = o;
    if (outB) {
        unsigned pk = (unsigned)f2bf(o.x) | ((unsigned)f2bf(o.y) << 16);
        *(unsigned*)(outB + (size_t)row * DD + lane * 2) = pk;
    }
}

__device__ __forceinline__ void pool_row_b(int row, int lane,
        const unsigned short* __restrict__ enc, const int* __restrict__ neigh,
        const int* __restrict__ cnt, unsigned short* __restrict__ P) {
    int c = cnt[row];
    const unsigned* e32 = (const unsigned*)enc;
    unsigned vv[KNBR];
#pragma unroll
    for (int j = 0; j < KNBR; ++j) {
        int nb = neigh[row * KNBR + j];
        int src = (j < c) ? nb : row;    // dead slots hit self row in L1
        vv[j] = e32[(size_t)src * 64 + lane];
    }
    float ax = -1e30f, ay = -1e30f;
#pragma unroll
    for (int j = 0; j < KNBR; ++j) {
        if (j < c) {
            ax = fmaxf(ax, __uint_as_float(vv[j] << 16));
            ay = fmaxf(ay, __uint_as_float(vv[j] & 0xFFFF0000u));
        }
    }
    unsigned o = 0u;
    if (c > 0)
        o = (__float_as_uint(ax) >> 16) | (__float_as_uint(ay) & 0xFFFF0000u);
    ((unsigned*)P)[(size_t)row * 64 + lane] = o;
}

__global__ __launch_bounds__(256)
void prop_pool_kernel(const float* __restrict__ nxt, const float* __restrict__ resid,
                      const float* __restrict__ dinv, const int* __restrict__ kept,
                      const int* __restrict__ neigh, const int* __restrict__ cnt,
                      const float* __restrict__ g, const float* __restrict__ b,
                      float* __restrict__ outH, int oStride, int oOff,
                      unsigned short* __restrict__ outHB,
                      const unsigned short* __restrict__ enc,
                      unsigned short* __restrict__ P) {
    int row = blockIdx.x * 4 + (threadIdx.x >> 6);
    int lane = threadIdx.x & 63;
    prop_ln_row(row, lane, nxt, resid, dinv, kept, neigh, g, b, outH, oStride, oOff, outHB);
    pool_row_b(row, lane, enc, neigh, cnt, P);
}

extern "C" void kernel_launch(void* const* d_in, const int* in_sizes, int n_in,
                              void* d_out, int out_size, void* d_ws, size_t ws_size,
                              hipStream_t stream) {
    (void)in_sizes; (void)n_in; (void)out_size; (void)ws_size;
    const float* x      = (const float*)d_in[0];
    const int*   neigh  = (const int*)d_in[1];
    const int*   cnt    = (const int*)d_in[2];
    const float* gcnW   = (const float*)d_in[3];
    const float* gcnB   = (const float*)d_in[4];
    const float* gcnG   = (const float*)d_in[5];
    const float* gcnBb  = (const float*)d_in[6];
    const float* poolW  = (const float*)d_in[7];
    const float* poolB  = (const float*)d_in[8];
    const float* mW     = (const float*)d_in[9];
    const float* mB     = (const float*)d_in[10];
    const float* sg     = (const float*)d_in[11];
    const float* sb     = (const float*)d_in[12];
    float* out = (float*)d_out;

    char* ws = (char*)d_ws;
    float* dinv = (float*)ws;                          // 32 KB
    int*   kept = (int*)(ws + 32 * 1024);              // 32 KB
    float* G  = (float*)(ws + 64 * 1024);              // fp32: 4 MB each
    float* H1 = G  + NND * DD;
    float* H2 = H1 + NND * DD;
    float* S1 = H2 + NND * DD;
    float* S2 = S1 + NND * DD;
    unsigned short* E1b = (unsigned short*)(S2 + NND * DD);  // bf16: 2 MB each
    unsigned short* Pb  = E1b + NND * DD;
    unsigned short* H1b = Pb  + NND * DD;
    unsigned short* H2b = H1b + NND * DD;
    unsigned short* S1b = H2b + NND * DD;
    unsigned short* S2b = S1b + NND * DD;

    dim3 blk(256);
    dim3 rgrid(NND / 4);

    // 1. [G0 | E1b | S1p] from x (+ degree/dedupe)
    mega_gemm<<<dim3(128, 3), blk, 0, stream>>>(x, gcnW, poolW, mW, gcnB, poolB, mB,
                                                neigh, cnt, dinv, kept, G, E1b, S1);
    // 2. H1(+b) = propLN(G0, resid=G0); P1b = pool(E1b)
    prop_pool_kernel<<<rgrid, blk, 0, stream>>>(G, G, dinv, kept, neigh, cnt,
                                                gcnG, gcnBb, H1, DD, 0, H1b, E1b, Pb);
    // 3. S1(+b) = relu(S1p + P1b@mW0R^T); G1 = H1b@gcnW1^T + b1
    gemm_step4<<<dim3(128, 2), blk, 0, stream>>>(Pb, H1b, mW, gcnW, gcnB + DD,
                                                 S1, S1b, G);
    // 4. H2(+b) = propLN(G1, resid=H1); P2b = pool(S1b)
    prop_pool_kernel<<<rgrid, blk, 0, stream>>>(G, H1, dinv, kept, neigh, cnt,
                                                gcnG + DD, gcnBb + DD, H2, DD, 0,
                                                H2b, S1b, Pb);
    // 5. S2(+b) = LN(relu([S1|P2]@mW1^T + mB1) + S1); G2 = H2b@gcnW2^T + b2
    gemm_step6<<<dim3(128, 2), blk, 0, stream>>>(S1b, Pb, H2b, S1, mW, gcnW,
                                                 mB + DD, gcnB + 2 * DD, sg, sb,
                                                 S2, S2b, G);
    // 6. outL = propLN(G2, resid=H2); P3b = pool(S2b)
    prop_pool_kernel<<<rgrid, blk, 0, stream>>>(G, H2, dinv, kept, neigh, cnt,
                                                gcnG + 2 * DD, gcnBb + 2 * DD,
                                                out, 2 * DD, 0, nullptr, S2b, Pb);
    // 7. outR = LN(relu([S2|P3]@mW2^T + mB2) + S2)
    gemm_final<<<dim3(128), blk, 0, stream>>>(S2b, Pb, S2, mW, mB + 2 * DD,
                                              sg + DD, sb + DD, out);
}

// Round 3
// 145.970 us; speedup vs baseline: 1.2637x; 1.0413x over previous
//
#include <hip/hip_runtime.h>

#define NND 8192
#define KNBR 8
#define DD 128
#define EPSF 1e-5f
#define TSH 16384      // shorts per 128x128 bf16 tile (32 KB)
#define XSTR 132       // LDS exchange row stride in floats (conflict-free)

typedef __attribute__((ext_vector_type(8))) short bf16x8;
typedef __attribute__((ext_vector_type(4))) float f32x4;

__device__ __forceinline__ unsigned short f2bf(float f) {
    unsigned u = __float_as_uint(f);
    u += 0x7FFF + ((u >> 16) & 1);   // round-to-nearest-even
    return (unsigned short)(u >> 16);
}

__device__ __forceinline__ bf16x8 cvt8(const float* __restrict__ p) {
    float4 lo = *(const float4*)p;
    float4 hi = *(const float4*)(p + 4);
    bf16x8 r;
    r[0] = f2bf(lo.x); r[1] = f2bf(lo.y); r[2] = f2bf(lo.z); r[3] = f2bf(lo.w);
    r[4] = f2bf(hi.x); r[5] = f2bf(hi.y); r[6] = f2bf(hi.z); r[7] = f2bf(hi.w);
    return r;
}

// ---- async weight staging: wbuf is pre-swizzled, copy linearly via DMA ----
__device__ __forceinline__ void gload_lds16(const unsigned short* g, unsigned short* l) {
    __builtin_amdgcn_global_load_lds(
        (const __attribute__((address_space(1))) unsigned int*)(g),
        (__attribute__((address_space(3))) unsigned int*)(l), 16, 0, 0);
}

template<int NT>
__device__ __forceinline__ void stageN(unsigned short* sh, const unsigned short* wb, int tid) {
    int lane = tid & 63, w = tid >> 6;
#pragma unroll
    for (int r = 0; r < NT * 8; ++r) {
        int blk = (r * 4 + w) * 512;          // shorts, wave-uniform
        gload_lds16(wb + blk + lane * 8, sh + blk);
    }
}

// ---- fragment loaders (issued BEFORE the staging barrier) ----
__device__ __forceinline__ void load_af(bf16x8* af, const unsigned short* __restrict__ A,
                                        int rowBase, int lane) {
    int idx = lane & 15, q = lane >> 4;
    const unsigned short* Ar = A + (size_t)(rowBase + idx) * DD;
#pragma unroll
    for (int s = 0; s < 4; ++s) af[s] = *(const bf16x8*)(Ar + s * 32 + q * 8);
}

__device__ __forceinline__ void load_af_f32(bf16x8* af, const float* __restrict__ A,
                                            int rowBase, int lane) {
    int idx = lane & 15, q = lane >> 4;
    const float* Ar = A + (size_t)(rowBase + idx) * DD;
#pragma unroll
    for (int s = 0; s < 4; ++s) af[s] = cvt8(Ar + s * 32 + q * 8);
}

// ---- full-width MFMA over a swizzled LDS tile: 16 rows x 128 cols, K=128 ----
__device__ __forceinline__ void mma_sw(const bf16x8* af, const unsigned short* shB,
                                       int lane, f32x4* acc) {
    int idx = lane & 15, q = lane >> 4, k7 = idx & 7;
#pragma unroll
    for (int s = 0; s < 4; ++s)
#pragma unroll
        for (int ct = 0; ct < 8; ++ct) {
            int ch = (4 * s + q) ^ k7;
            bf16x8 bf = *(const bf16x8*)(shB + (ct * 16 + idx) * 128 + ch * 8);
            acc[ct] = __builtin_amdgcn_mfma_f32_16x16x32_bf16(af[s], bf, acc[ct], 0, 0, 0);
        }
}

__device__ __forceinline__ void store_fw(float* __restrict__ out, int ostride, int oOff,
        int rowBase, int lane, const f32x4* acc, const float* __restrict__ bias, bool relu) {
    int idx = lane & 15, q = lane >> 4;
#pragma unroll
    for (int ct = 0; ct < 8; ++ct) {
        float b = bias[ct * 16 + idx];
#pragma unroll
        for (int r = 0; r < 4; ++r) {
            float v = acc[ct][r] + b;
            if (relu) v = fmaxf(v, 0.f);
            out[(size_t)(rowBase + q * 4 + r) * ostride + oOff + ct * 16 + idx] = v;
        }
    }
}

__device__ __forceinline__ void store_fw_b16(unsigned short* __restrict__ out,
        int rowBase, int lane, const f32x4* acc, const float* __restrict__ bias) {
    int idx = lane & 15, q = lane >> 4;
#pragma unroll
    for (int ct = 0; ct < 8; ++ct) {
        float b = bias[ct * 16 + idx];
#pragma unroll
        for (int r = 0; r < 4; ++r)
            out[(size_t)(rowBase + q * 4 + r) * DD + ct * 16 + idx]
                = f2bf(fmaxf(acc[ct][r] + b, 0.f));
    }
}

// Fused epilogue: v = relu(acc+bias) + resid;  out = LN(v)*g + b  (+ optional bf16 copy).
__device__ __forceinline__ void lnstore_fw(float* __restrict__ out, int ostride, int oOff,
        const float* __restrict__ resid, int rowBase, int lane, f32x4* acc,
        const float* __restrict__ bias, const float* __restrict__ g,
        const float* __restrict__ bv, unsigned short* __restrict__ outB) {
    int idx = lane & 15, q = lane >> 4;
    float rsum[4] = {0.f, 0.f, 0.f, 0.f};
#pragma unroll
    for (int ct = 0; ct < 8; ++ct) {
        float b = bias[ct * 16 + idx];
#pragma unroll
        for (int r = 0; r < 4; ++r) {
            float t = fmaxf(acc[ct][r] + b, 0.f)
                    + resid[(size_t)(rowBase + q * 4 + r) * DD + ct * 16 + idx];
            acc[ct][r] = t;
            rsum[r] += t;
        }
    }
#pragma unroll
    for (int r = 0; r < 4; ++r)
#pragma unroll
        for (int m = 1; m < 16; m <<= 1) rsum[r] += __shfl_xor(rsum[r], m, 64);
    float mu[4];
#pragma unroll
    for (int r = 0; r < 4; ++r) mu[r] = rsum[r] * (1.f / 128.f);
    float var[4] = {0.f, 0.f, 0.f, 0.f};
#pragma unroll
    for (int ct = 0; ct < 8; ++ct)
#pragma unroll
        for (int r = 0; r < 4; ++r) {
            float d = acc[ct][r] - mu[r];
            var[r] += d * d;
        }
#pragma unroll
    for (int r = 0; r < 4; ++r)
#pragma unroll
        for (int m = 1; m < 16; m <<= 1) var[r] += __shfl_xor(var[r], m, 64);
    float rs[4];
#pragma unroll
    for (int r = 0; r < 4; ++r) rs[r] = rsqrtf(var[r] * (1.f / 128.f) + EPSF);
#pragma unroll
    for (int ct = 0; ct < 8; ++ct) {
        float gg = g[ct * 16 + idx], bb = bv[ct * 16 + idx];
#pragma unroll
        for (int r = 0; r < 4; ++r) {
            float o = (acc[ct][r] - mu[r]) * rs[r] * gg + bb;
            size_t row = (size_t)(rowBase + q * 4 + r);
            out[row * ostride + oOff + ct * 16 + idx] = o;
            if (outB) outB[row * DD + ct * 16 + idx] = f2bf(o);
        }
    }
}

// ---------------------------------------------------------------------------
// cvt_deg: grid(112). x<32: degree/dedupe. x>=32: fp32->bf16 weight convert
// into pre-swizzled wbuf (10 tiles: gcnW0/1/2, poolW, mW0L/R, mW1L/R, mW2L/R).
// Swizzle: 16B chunk ch of row stored at ch ^ (row&7).
// ---------------------------------------------------------------------------
__global__ __launch_bounds__(256)
void cvt_deg(const int* __restrict__ neigh, const int* __restrict__ cnt,
             const float* __restrict__ gcnW, const float* __restrict__ poolW,
             const float* __restrict__ mW,
             float* __restrict__ dinv, int* __restrict__ kept,
             unsigned short* __restrict__ wbuf) {
    int bx = blockIdx.x, tid = threadIdx.x;
    if (bx < 32) {
        int i = bx * 256 + tid;
        int c = cnt[i];
        int nb[KNBR];
#pragma unroll
        for (int j = 0; j < KNBR; ++j) nb[j] = neigh[i * KNBR + j];
        int mask = 0, deg = 1;
#pragma unroll
        for (int j = 0; j < KNBR; ++j) {
            if (j < c) {
                int v = nb[j];
                bool dup = (v == i);
                for (int jj = 0; jj < j; ++jj)
                    if (nb[jj] == v) { dup = true; }
                if (!dup) { mask |= (1 << j); deg++; }
            }
        }
        dinv[i] = rsqrtf((float)deg);
        kept[i] = mask;
    } else {
        int cid = (bx - 32) * 256 + tid;      // 0..20479 chunk id (8 floats each)
        int t = cid >> 11, c2 = cid & 2047, row = c2 >> 4, ch = c2 & 15;
        const float* base; int str;
        if (t < 3)       { base = gcnW + t * 16384; str = 128; }
        else if (t == 3) { base = poolW; str = 128; }
        else { int u = t - 4; base = mW + (u >> 1) * 32768 + (u & 1) * 128; str = 256; }
        bf16x8 v = cvt8(base + (size_t)row * str + ch * 8);
        *(bf16x8*)(wbuf + t * TSH + row * 128 + ((ch ^ (row & 7)) << 3)) = v;
    }
}

// ---------------------------------------------------------------------------
// mega: grid (128, 3). y0: G0 = x@gcnW0^T + gB0
//                      y1: E1b = bf16(relu(x@poolW^T + pB))
//                      y2: S1p = x@mW0L^T + mB0
// ---------------------------------------------------------------------------
__global__ __launch_bounds__(256)
void mega_gemm(const float* __restrict__ x, const unsigned short* __restrict__ wbuf,
               const float* __restrict__ gB0, const float* __restrict__ pB,
               const float* __restrict__ mB0,
               float* __restrict__ G, unsigned short* __restrict__ E1b,
               float* __restrict__ S) {
    __shared__ __align__(16) unsigned short shB[TSH];
    const int tid = threadIdx.x, lane = tid & 63, w = tid >> 6;
    const int grp = blockIdx.y;
    const int tile = (grp == 0) ? 0 : (grp == 1) ? 3 : 4;
    stageN<1>(shB, wbuf + tile * TSH, tid);
    const int rowBase = ((int)blockIdx.x * 4 + w) * 16;
    bf16x8 af[4];
    load_af_f32(af, x, rowBase, lane);
    __syncthreads();
    f32x4 acc[8];
#pragma unroll
    for (int i = 0; i < 8; ++i) acc[i] = (f32x4){0.f, 0.f, 0.f, 0.f};
    mma_sw(af, shB, lane, acc);
    if (grp == 0)      store_fw(G, DD, 0, rowBase, lane, acc, gB0, false);
    else if (grp == 1) store_fw_b16(E1b, rowBase, lane, acc, pB);
    else               store_fw(S, DD, 0, rowBase, lane, acc, mB0, false);
}

// step4: grid (128, 2). y0: S1 = relu(S1p + P1b@mW0R^T) (RMW) + bf16 copy
//                       y1: G1 = H1b@gcnW1^T + gB1
__global__ __launch_bounds__(256)
void gemm_step4(const unsigned short* __restrict__ Pb, const unsigned short* __restrict__ H1b,
                const unsigned short* __restrict__ wbuf, const float* __restrict__ gB1,
                float* __restrict__ S, unsigned short* __restrict__ S1b,
                float* __restrict__ G) {
    __shared__ __align__(16) unsigned short shB[TSH];
    const int tid = threadIdx.x, lane = tid & 63, w = tid >> 6;
    const int rowBase = ((int)blockIdx.x * 4 + w) * 16;
    f32x4 acc[8];
#pragma unroll
    for (int i = 0; i < 8; ++i) acc[i] = (f32x4){0.f, 0.f, 0.f, 0.f};
    bf16x8 af[4];
    if (blockIdx.y == 0) {
        stageN<1>(shB, wbuf + 5 * TSH, tid);   // mW0R
        load_af(af, Pb, rowBase, lane);
        __syncthreads();
        mma_sw(af, shB, lane, acc);
        int idx = lane & 15, q = lane >> 4;
#pragma unroll
        for (int ct = 0; ct < 8; ++ct)
#pragma unroll
            for (int r = 0; r < 4; ++r) {
                size_t o = (size_t)(rowBase + q * 4 + r) * DD + ct * 16 + idx;
                float v = fmaxf(S[o] + acc[ct][r], 0.f);
                S[o] = v;
                S1b[o] = f2bf(v);
            }
    } else {
        stageN<1>(shB, wbuf + 1 * TSH, tid);   // gcnW1
        load_af(af, H1b, rowBase, lane);
        __syncthreads();
        mma_sw(af, shB, lane, acc);
        store_fw(G, DD, 0, rowBase, lane, acc, gB1, false);
    }
}

// step6: grid (128, 2).
//  y0: S2 = LN(relu([S1|P2]@mW1^T + mB1) + S1) (+bf16 copy)
//  y1: G2 = H2b@gcnW2^T + gB2
__global__ __launch_bounds__(256)
void gemm_step6(const unsigned short* __restrict__ S1b, const unsigned short* __restrict__ Pb,
                const unsigned short* __restrict__ H2b, const float* __restrict__ S1,
                const unsigned short* __restrict__ wbuf,
                const float* __restrict__ mB1, const float* __restrict__ gB2,
                const float* __restrict__ sg, const float* __restrict__ sb,
                float* __restrict__ S2, unsigned short* __restrict__ S2b,
                float* __restrict__ G) {
    __shared__ __align__(16) unsigned short shB[2 * TSH];
    const int tid = threadIdx.x, lane = tid & 63, w = tid >> 6;
    const int rowBase = ((int)blockIdx.x * 4 + w) * 16;
    f32x4 acc[8];
#pragma unroll
    for (int i = 0; i < 8; ++i) acc[i] = (f32x4){0.f, 0.f, 0.f, 0.f};
    if (blockIdx.y == 0) {
        stageN<2>(shB, wbuf + 6 * TSH, tid);   // mW1L | mW1R (contiguous)
        bf16x8 af1[4], af2[4];
        load_af(af1, S1b, rowBase, lane);
        load_af(af2, Pb, rowBase, lane);
        __syncthreads();
        mma_sw(af1, shB, lane, acc);
        mma_sw(af2, shB + TSH, lane, acc);
        lnstore_fw(S2, DD, 0, S1, rowBase, lane, acc, mB1, sg, sb, S2b);
    } else {
        stageN<1>(shB, wbuf + 2 * TSH, tid);   // gcnW2
        bf16x8 af[4];
        load_af(af, H2b, rowBase, lane);
        __syncthreads();
        mma_sw(af, shB, lane, acc);
        store_fw(G, DD, 0, rowBase, lane, acc, gB2, false);
    }
}

// final: grid (256). out[:, D:] = LN(relu([S2|P3]@mW2^T + mB2) + S2)
// K=256 split across wave pairs: waves 0,1 do unit0 (S2b), waves 2,3 unit1 (Pb);
// partials combined through padded LDS exchange, LN epilogue on waves 0,1.
__global__ __launch_bounds__(256)
void gemm_final(const unsigned short* __restrict__ S2b, const unsigned short* __restrict__ Pb,
                const float* __restrict__ S2, const unsigned short* __restrict__ wbuf,
                const float* __restrict__ mB2,
                const float* __restrict__ sg2, const float* __restrict__ sb2,
                float* __restrict__ out) {
    __shared__ __align__(16) unsigned short shB[2 * TSH];
    __shared__ float xch[32 * XSTR];
    const int tid = threadIdx.x, lane = tid & 63, w = tid >> 6;
    stageN<2>(shB, wbuf + 8 * TSH, tid);       // mW2L | mW2R
    const int rowBase = (int)blockIdx.x * 32 + (w & 1) * 16;
    const int unit = w >> 1;
    bf16x8 af[4];
    load_af(af, unit ? Pb : S2b, rowBase, lane);
    __syncthreads();
    f32x4 acc[8];
#pragma unroll
    for (int i = 0; i < 8; ++i) acc[i] = (f32x4){0.f, 0.f, 0.f, 0.f};
    mma_sw(af, shB + unit * TSH, lane, acc);
    int idx = lane & 15, q = lane >> 4;
    if (unit) {
#pragma unroll
        for (int ct = 0; ct < 8; ++ct)
#pragma unroll
            for (int r = 0; r < 4; ++r)
                xch[((w & 1) * 16 + q * 4 + r) * XSTR + ct * 16 + idx] = acc[ct][r];
    }
    __syncthreads();
    if (!unit) {
#pragma unroll
        for (int ct = 0; ct < 8; ++ct)
#pragma unroll
            for (int r = 0; r < 4; ++r)
                acc[ct][r] += xch[((w & 1) * 16 + q * 4 + r) * XSTR + ct * 16 + idx];
        lnstore_fw(out, 2 * DD, DD, S2, rowBase, lane, acc, mB2, sg2, sb2, nullptr);
    }
}

// ---------------------------------------------------------------------------
// Row-wise: prop+LN (fp32 gathers, de-serialized) and bf16 max-pool.
// ---------------------------------------------------------------------------
__device__ __forceinline__ float wave_sum(float s) {
#pragma unroll
    for (int m = 1; m < 64; m <<= 1) s += __shfl_xor(s, m, 64);
    return s;
}

__device__ __forceinline__ void prop_ln_row(int row, int lane,
        const float* __restrict__ nxt, const float* __restrict__ resid,
        const float* __restrict__ dinv, const int* __restrict__ kept,
        const int* __restrict__ neigh,
        const float* __restrict__ g, const float* __restrict__ b,
        float* __restrict__ out, int oStride, int oOff,
        unsigned short* __restrict__ outB) {
    const float2* nxt2 = (const float2*)nxt;
    float di = dinv[row];
    int km = kept[row];
    int idxs[KNBR]; float wj[KNBR];
#pragma unroll
    for (int j = 0; j < KNBR; ++j) {
        int nb = neigh[row * KNBR + j];
        bool k = (km >> j) & 1;
        idxs[j] = k ? nb : row;
        wj[j] = k ? dinv[nb] : 0.f;
    }
    float2 vv[KNBR];
#pragma unroll
    for (int j = 0; j < KNBR; ++j) vv[j] = nxt2[(size_t)idxs[j] * 64 + lane];
    float2 self = nxt2[(size_t)row * 64 + lane];
    float ax = di * self.x, ay = di * self.y;
#pragma unroll
    for (int j = 0; j < KNBR; ++j) {
        ax = fmaf(wj[j], vv[j].x, ax);
        ay = fmaf(wj[j], vv[j].y, ay);
    }
    float2 r = ((const float2*)resid)[(size_t)row * 64 + lane];
    float vx = fmaxf(di * ax, 0.f) + r.x;
    float vy = fmaxf(di * ay, 0.f) + r.y;
    float mu = wave_sum(vx + vy) * (1.f / 128.f);
    float dx = vx - mu, dy = vy - mu;
    float var = wave_sum(dx * dx + dy * dy) * (1.f / 128.f);
    float rs = rsqrtf(var + EPSF);
    float2 gg = ((const float2*)g)[lane];
    float2 bb = ((const float2*)b)[lane];
    float2 o;
    o.x = dx * rs * gg.x + bb.x;
    o.y = dy * rs * gg.y + bb.y;
    *reinterpret_cast<float2*>(out + (size_t)row * oStride + oOff + lane * 2) = o;
    if (outB) {
        unsigned pk = (unsigned)f2bf(o.x) | ((unsigned)f2bf(o.y) << 16);
        *(unsigned*)(outB + (size_t)row * DD + lane * 2) = pk;
    }
}

__device__ __forceinline__ void pool_row_b(int row, int lane,
        const unsigned short* __restrict__ enc, const int* __restrict__ neigh,
        const int* __restrict__ cnt, unsigned short* __restrict__ P) {
    int c = cnt[row];
    const unsigned* e32 = (const unsigned*)enc;
    unsigned vv[KNBR];
#pragma unroll
    for (int j = 0; j < KNBR; ++j) {
        int nb = neigh[row * KNBR + j];
        int src = (j < c) ? nb : row;
        vv[j] = e32[(size_t)src * 64 + lane];
    }
    float ax = -1e30f, ay = -1e30f;
#pragma unroll
    for (int j = 0; j < KNBR; ++j) {
        if (j < c) {
            ax = fmaxf(ax, __uint_as_float(vv[j] << 16));
            ay = fmaxf(ay, __uint_as_float(vv[j] & 0xFFFF0000u));
        }
    }
    unsigned o = 0u;
    if (c > 0)
        o = (__float_as_uint(ax) >> 16) | (__float_as_uint(ay) & 0xFFFF0000u);
    ((unsigned*)P)[(size_t)row * 64 + lane] = o;
}

__global__ __launch_bounds__(256)
void prop_pool_kernel(const float* __restrict__ nxt, const float* __restrict__ resid,
                      const float* __restrict__ dinv, const int* __restrict__ kept,
                      const int* __restrict__ neigh, const int* __restrict__ cnt,
                      const float* __restrict__ g, const float* __restrict__ b,
                      float* __restrict__ outH, int oStride, int oOff,
                      unsigned short* __restrict__ outHB,
                      const unsigned short* __restrict__ enc,
                      unsigned short* __restrict__ P) {
    int row = blockIdx.x * 4 + (threadIdx.x >> 6);
    int lane = threadIdx.x & 63;
    prop_ln_row(row, lane, nxt, resid, dinv, kept, neigh, g, b, outH, oStride, oOff, outHB);
    pool_row_b(row, lane, enc, neigh, cnt, P);
}

extern "C" void kernel_launch(void* const* d_in, const int* in_sizes, int n_in,
                              void* d_out, int out_size, void* d_ws, size_t ws_size,
                              hipStream_t stream) {
    (void)in_sizes; (void)n_in; (void)out_size; (void)ws_size;
    const float* x      = (const float*)d_in[0];
    const int*   neigh  = (const int*)d_in[1];
    const int*   cnt    = (const int*)d_in[2];
    const float* gcnW   = (const float*)d_in[3];
    const float* gcnB   = (const float*)d_in[4];
    const float* gcnG   = (const float*)d_in[5];
    const float* gcnBb  = (const float*)d_in[6];
    const float* poolW  = (const float*)d_in[7];
    const float* poolB  = (const float*)d_in[8];
    const float* mW     = (const float*)d_in[9];
    const float* mB     = (const float*)d_in[10];
    const float* sg     = (const float*)d_in[11];
    const float* sb     = (const float*)d_in[12];
    float* out = (float*)d_out;

    char* ws = (char*)d_ws;
    float* dinv = (float*)ws;                                // 32 KB
    int*   kept = (int*)(ws + 32 * 1024);                    // 32 KB
    unsigned short* wbuf = (unsigned short*)(ws + 64 * 1024);// 320 KB (10 tiles)
    float* G  = (float*)(ws + 448 * 1024);                   // fp32: 4 MB each
    float* H1 = G  + NND * DD;
    float* H2 = H1 + NND * DD;
    float* S1 = H2 + NND * DD;
    float* S2 = S1 + NND * DD;
    unsigned short* E1b = (unsigned short*)(S2 + NND * DD);  // bf16: 2 MB each
    unsigned short* Pb  = E1b + NND * DD;
    unsigned short* H1b = Pb  + NND * DD;
    unsigned short* H2b = H1b + NND * DD;
    unsigned short* S1b = H2b + NND * DD;
    unsigned short* S2b = S1b + NND * DD;

    dim3 blk(256);
    dim3 rgrid(NND / 4);

    // 0. degree/dedupe + bf16 pre-swizzled weight buffer
    cvt_deg<<<dim3(112), blk, 0, stream>>>(neigh, cnt, gcnW, poolW, mW,
                                           dinv, kept, wbuf);
    // 1. [G0 | E1b | S1p] from x
    mega_gemm<<<dim3(128, 3), blk, 0, stream>>>(x, wbuf, gcnB, poolB, mB, G, E1b, S1);
    // 2. H1(+b) = propLN(G0, resid=G0); P1b = pool(E1b)
    prop_pool_kernel<<<rgrid, blk, 0, stream>>>(G, G, dinv, kept, neigh, cnt,
                                                gcnG, gcnBb, H1, DD, 0, H1b, E1b, Pb);
    // 3. S1(+b) = relu(S1p + P1b@mW0R^T); G1 = H1b@gcnW1^T + b1
    gemm_step4<<<dim3(128, 2), blk, 0, stream>>>(Pb, H1b, wbuf, gcnB + DD,
                                                 S1, S1b, G);
    // 4. H2(+b) = propLN(G1, resid=H1); P2b = pool(S1b)
    prop_pool_kernel<<<rgrid, blk, 0, stream>>>(G, H1, dinv, kept, neigh, cnt,
                                                gcnG + DD, gcnBb + DD, H2, DD, 0,
                                                H2b, S1b, Pb);
    // 5. S2(+b) = LN(relu([S1|P2]@mW1^T + mB1) + S1); G2 = H2b@gcnW2^T + b2
    gemm_step6<<<dim3(128, 2), blk, 0, stream>>>(S1b, Pb, H2b, S1, wbuf,
                                                 mB + DD, gcnB + 2 * DD, sg, sb,
                                                 S2, S2b, G);
    // 6. outL = propLN(G2, resid=H2); P3b = pool(S2b)
    prop_pool_kernel<<<rgrid, blk, 0, stream>>>(G, H2, dinv, kept, neigh, cnt,
                                                gcnG + 2 * DD, gcnBb + 2 * DD,
                                                out, 2 * DD, 0, nullptr, S2b, Pb);
    // 7. outR = LN(relu([S2|P3]@mW2^T + mB2) + S2)
    gemm_final<<<dim3(256), blk, 0, stream>>>(S2b, Pb, S2, wbuf, mB + 2 * DD,
                                              sg + DD, sb + DD, out);
}